// Round 2
// baseline (138.371 us; speedup 1.0000x reference)
//
#include <hip/hip_runtime.h>
#include <hip/hip_bf16.h>

#define BATCH   32
#define TLEN    128000
#define FGAIN   1000
#define ORDER   26
#define WLEN    512
#define HOP     128
#define PAD     192                 // (512-128)/2
#define TPAD    (TLEN + 2*PAD)      // 128384 padded length
#define NFRAME  1000
#define NTOT    (BATCH*NFRAME)      // 32000 frames total

// ---------------------------------------------------------------------------
// Kernel 1: exg_padded[b][p] = (PAD <= p < PAD+TLEN) ? ex[b][p-PAD] * ug(b, p-PAD) : 0
// ug = linear upsample of gain (F=1000 -> T=128000, hop=128).
// src arithmetic is exact in f32 (numerator fits mantissa; /128 is pow2),
// so i0/w match the JAX reference exactly.
// ---------------------------------------------------------------------------
__global__ __launch_bounds__(256) void k_exg(const float* __restrict__ ex,
                                             const float* __restrict__ gain,
                                             float* __restrict__ exg) {
  int gid = blockIdx.x * 256 + threadIdx.x;   // one thread per 4 elements
  const int total4 = BATCH * TPAD / 4;
  if (gid >= total4) return;
  int idx = gid * 4;
  int b  = idx / TPAD;
  int r0 = idx - b * TPAD;
  const float* __restrict__ gr  = gain + b * FGAIN;
  const float* __restrict__ exr = ex + (size_t)b * TLEN;
  float v[4];
#pragma unroll
  for (int c = 0; c < 4; ++c) {
    int j = r0 + c - PAD;
    float val = 0.0f;
    if (j >= 0 && j < TLEN) {
      float src = ((float)j + 0.5f) * (1.0f / (float)HOP) - 0.5f;
      src = fminf(fmaxf(src, 0.0f), (float)(FGAIN - 1));
      int   i0 = (int)src;                 // floor (src >= 0)
      float w  = src - (float)i0;
      int   i1 = (i0 < FGAIN - 1) ? i0 + 1 : FGAIN - 1;
      float g  = gr[i0] * (1.0f - w) + gr[i1] * w;
      val = exr[j] * g;
    }
    v[c] = val;
  }
  float4 o = make_float4(v[0], v[1], v[2], v[3]);
  *reinterpret_cast<float4*>(exg + idx) = o;
}

// ---------------------------------------------------------------------------
// Kernel 2: per-frame order-26 IIR synthesis. One frame per lane.
// fw[b][n][t] = y[t],  y[t] = x[t] - sum_k a[k]*y[t-1-k], zero initial state.
// History kept in registers via a circular buffer; time loop unrolled in
// blocks of 26 so all slot indices constant-fold (no scratch).
// Accumulation starts from xv and uses p -= a*h (emits v_fma with -modifier).
// Tap 0 applied LAST so the cross-step critical path is a single FMA.
// ---------------------------------------------------------------------------
__global__ __launch_bounds__(64) void k_lpc(const float* __restrict__ exg,
                                            const float* __restrict__ acoef,
                                            float* __restrict__ fw) {
  int f = blockIdx.x * 64 + threadIdx.x;
  if (f >= NTOT) return;
  int b = f / NFRAME;
  int n = f - b * NFRAME;
  const float* __restrict__ x  = exg + (size_t)b * TPAD + n * HOP;
  const float* __restrict__ ap = acoef + (size_t)f * ORDER;
  float* __restrict__ op = fw + (size_t)f * WLEN;

  float a[ORDER], h[ORDER];
#pragma unroll
  for (int k = 0; k < ORDER; ++k) { a[k] = ap[k]; h[k] = 0.0f; }

  // slot(m) at global time t+s (t % 26 == 0): h[m] holds the most recent
  // y at time == m (mod 26). For step s we need y[t+s-1-k] in slot
  // ((s-1-k) mod 26); all indices below are compile-time constants.
#define LPC_STEP(s) {                                                      \
    float xv = x[t + (s)];                                                 \
    float p0 = xv, p1 = 0.f, p2 = 0.f, p3 = 0.f;                           \
    _Pragma("unroll")                                                      \
    for (int k = 1; k < ORDER; ++k) {                                      \
      float hv = h[((s) - 1 - k + 2*ORDER) % ORDER];                       \
      int sel = k & 3;                                                     \
      if      (sel == 0) p0 -= a[k] * hv;                                  \
      else if (sel == 1) p1 -= a[k] * hv;                                  \
      else if (sel == 2) p2 -= a[k] * hv;                                  \
      else               p3 -= a[k] * hv;                                  \
    }                                                                      \
    float rest = (p0 + p1) + (p2 + p3);                                    \
    float y = rest - a[0] * h[((s) + ORDER - 1) % ORDER];                  \
    h[(s)] = y;                                                            \
    op[t + (s)] = y;                                                       \
  }

  int t = 0;
  // 512 = 26*19 + 18
  for (int blk = 0; blk < 19; ++blk) {
#pragma unroll
    for (int s = 0; s < ORDER; ++s) {
      LPC_STEP(s)
    }
    t += ORDER;
  }
  // epilogue: t = 494 (multiple of 26), 18 remaining steps
#pragma unroll
  for (int s = 0; s < 18; ++s) {
    LPC_STEP(s)
  }
#undef LPC_STEP
}

// ---------------------------------------------------------------------------
// Kernel 3: windowed overlap-add + normalization.
// out[b][j] = ( sum_n fw[b][n][p-128n] * win[p-128n] ) / ( sum_n win[p-128n] ),
// p = j + PAD, n over the <=4 overlapping frames. 4 outputs per thread.
// p0 and all w0 are multiples of 4, so every frame either covers all 4
// samples or none (w0 in {0..508}) -> no partial-coverage edge case, and
// all float4 accesses are 16B-aligned.
// ---------------------------------------------------------------------------
__global__ __launch_bounds__(256) void k_ola(const float* __restrict__ fw,
                                             const float* __restrict__ win,
                                             float* __restrict__ out) {
  int gid = blockIdx.x * 256 + threadIdx.x;   // one thread per 4 outputs
  const int total4 = BATCH * TLEN / 4;
  if (gid >= total4) return;
  int idx = gid * 4;
  int b  = idx / TLEN;
  int j0 = idx - b * TLEN;
  int p0 = j0 + PAD;

  // frames n with 0 <= p0-128n <= 508:  ceil((p0-508)/128) == (p0-381)/128
  int lo = (p0 - 381) / HOP;
  if (lo < 0) lo = 0;
  int hi = p0 / HOP;
  if (hi > NFRAME - 1) hi = NFRAME - 1;

  float ax = 0.f, ay = 0.f, az = 0.f, aw = 0.f;
  float nx = 0.f, ny = 0.f, nz = 0.f, nw = 0.f;
  for (int n = lo; n <= hi; ++n) {
    int w0 = p0 - n * HOP;       // 0..508, multiple of 4
    const float4 fv = *reinterpret_cast<const float4*>(fw + ((size_t)b * NFRAME + n) * WLEN + w0);
    const float4 wv = *reinterpret_cast<const float4*>(win + w0);
    ax += fv.x * wv.x;  ay += fv.y * wv.y;  az += fv.z * wv.z;  aw += fv.w * wv.w;
    nx += wv.x;         ny += wv.y;         nz += wv.z;         nw += wv.w;
  }
  float4 o = make_float4(ax / nx, ay / ny, az / nz, aw / nw);
  *reinterpret_cast<float4*>(out + idx) = o;
}

// ---------------------------------------------------------------------------
extern "C" void kernel_launch(void* const* d_in, const int* in_sizes, int n_in,
                              void* d_out, int out_size, void* d_ws, size_t ws_size,
                              hipStream_t stream) {
  const float* ex   = (const float*)d_in[0];   // [32][128000]
  const float* gain = (const float*)d_in[1];   // [32][1000]
  const float* a    = (const float*)d_in[2];   // [32][1000][26]
  const float* win  = (const float*)d_in[3];   // [512]
  // d_in[4] = hop_length (=128, compile-time constant here)
  float* outp = (float*)d_out;                 // [32][128000]

  // workspace layout: exg_padded [32][128384] f32, then fw [32][1000][512] f32
  float* exg = (float*)d_ws;
  float* fw  = exg + (size_t)BATCH * TPAD;     // byte offset 16,433,152 (16B aligned)
  // total ws usage: (4,108,288 + 16,384,000) * 4 B ~= 82 MB

  {
    int total4 = BATCH * TPAD / 4;
    int blocks = (total4 + 255) / 256;
    hipLaunchKernelGGL(k_exg, dim3(blocks), dim3(256), 0, stream, ex, gain, exg);
  }
  {
    int blocks = (NTOT + 63) / 64;             // 500 blocks x 64
    hipLaunchKernelGGL(k_lpc, dim3(blocks), dim3(64), 0, stream, exg, a, fw);
  }
  {
    int total4 = BATCH * TLEN / 4;
    int blocks = (total4 + 255) / 256;
    hipLaunchKernelGGL(k_ola, dim3(blocks), dim3(256), 0, stream, fw, win, outp);
  }
}

// Round 3
// 130.100 us; speedup vs baseline: 1.0636x; 1.0636x over previous
//
#include <hip/hip_runtime.h>
#include <hip/hip_bf16.h>

#define BATCH   32
#define TLEN    128000
#define FGAIN   1000
#define ORDER   26
#define WLEN    512
#define HOP     128
#define PAD     192                 // (512-128)/2
#define TPAD    (TLEN + 2*PAD)      // 128384 padded length
#define NFRAME  1000
#define NTOT    (BATCH*NFRAME)      // 32000 frames total

// ---------------------------------------------------------------------------
// Kernel 1: exg_padded[b][p] = (PAD <= p < PAD+TLEN) ? ex[b][p-PAD] * ug(b, p-PAD) : 0
// ug = linear upsample of gain (F=1000 -> T=128000, hop=128).
// src arithmetic exact in f32 -> i0/w match the JAX reference bit-for-bit.
// ---------------------------------------------------------------------------
__global__ __launch_bounds__(256) void k_exg(const float* __restrict__ ex,
                                             const float* __restrict__ gain,
                                             float* __restrict__ exg) {
  int gid = blockIdx.x * 256 + threadIdx.x;   // one thread per 4 elements
  const int total4 = BATCH * TPAD / 4;
  if (gid >= total4) return;
  int idx = gid * 4;
  int b  = idx / TPAD;
  int r0 = idx - b * TPAD;
  const float* __restrict__ gr  = gain + b * FGAIN;
  const float* __restrict__ exr = ex + (size_t)b * TLEN;
  float v[4];
#pragma unroll
  for (int c = 0; c < 4; ++c) {
    int j = r0 + c - PAD;
    float val = 0.0f;
    if (j >= 0 && j < TLEN) {
      float src = ((float)j + 0.5f) * (1.0f / (float)HOP) - 0.5f;
      src = fminf(fmaxf(src, 0.0f), (float)(FGAIN - 1));
      int   i0 = (int)src;                 // floor (src >= 0)
      float w  = src - (float)i0;
      int   i1 = (i0 < FGAIN - 1) ? i0 + 1 : FGAIN - 1;
      float g  = gr[i0] * (1.0f - w) + gr[i1] * w;
      val = exr[j] * g;
    }
    v[c] = val;
  }
  float4 o = make_float4(v[0], v[1], v[2], v[3]);
  *reinterpret_cast<float4*>(exg + idx) = o;
}

// ---------------------------------------------------------------------------
// Kernel 2: per-frame order-26 IIR synthesis. One frame per lane.
// y[t] = x[t] - sum_k a[k]*y[t-1-k], zero initial state, 512 steps.
//
// R2 counters showed this kernel is scattered-VMEM-bound (64 distinct cache
// lines per wave64 memory op; VALUBusy 19.8%). Fix: 52-step superblocks
// (52 = 13 x float4, 52 % 26 == 0 so circular-history indices constant-fold).
// Per superblock: 13 x float4 load -> buf[52], 52 unrolled IIR steps writing
// y back into buf, 13 x float4 store. VMEM instrs/wave: 1024 -> ~270.
// All vector accesses 16B-aligned (208-byte superblock stride, 512B bases).
// Tap 0 applied LAST so the cross-step critical path is a single FMA.
// ---------------------------------------------------------------------------
__global__ __launch_bounds__(64) void k_lpc(const float* __restrict__ exg,
                                            const float* __restrict__ acoef,
                                            float* __restrict__ fw) {
  int f = blockIdx.x * 64 + threadIdx.x;      // grid is exact: 500*64 == 32000
  int b = f / NFRAME;
  int n = f - b * NFRAME;
  const float* __restrict__ x  = exg + (size_t)b * TPAD + n * HOP;
  const float* __restrict__ ap = acoef + (size_t)f * ORDER;
  float* __restrict__ op = fw + (size_t)f * WLEN;

  float a[ORDER], h[ORDER];
  // coefficient load: 13 x float2 (per-lane base f*104 B is 8B-aligned)
#pragma unroll
  for (int q = 0; q < 13; ++q) {
    float2 v = *reinterpret_cast<const float2*>(ap + 2 * q);
    a[2 * q] = v.x;  a[2 * q + 1] = v.y;
  }
#pragma unroll
  for (int k = 0; k < ORDER; ++k) h[k] = 0.0f;

  float buf[52];

  // Invariant at step s (t % 26 == 0): h[m] holds the newest y at time
  // congruent to m (mod 26). Need y[t+s-1-k] -> slot ((s-1-k) mod 26).
  // All indices below are compile-time constants after unrolling.
#define LPC_STEP(s) {                                                      \
    float xv = buf[(s)];                                                   \
    float p0 = xv, p1 = 0.f, p2 = 0.f, p3 = 0.f;                           \
    _Pragma("unroll")                                                      \
    for (int k = 1; k < ORDER; ++k) {                                      \
      float hv = h[((s) - 1 - k + 2 * ORDER) % ORDER];                     \
      int sel = k & 3;                                                     \
      if      (sel == 0) p0 -= a[k] * hv;                                  \
      else if (sel == 1) p1 -= a[k] * hv;                                  \
      else if (sel == 2) p2 -= a[k] * hv;                                  \
      else               p3 -= a[k] * hv;                                  \
    }                                                                      \
    float rest = (p0 + p1) + (p2 + p3);                                    \
    float y = rest - a[0] * h[((s) + ORDER - 1) % ORDER];                  \
    h[(s) % ORDER] = y;                                                    \
    buf[(s)] = y;                                                          \
  }

  int t = 0;
  for (int sb = 0; sb < 9; ++sb) {            // 9 * 52 = 468
#pragma unroll
    for (int q = 0; q < 13; ++q) {
      float4 v = *reinterpret_cast<const float4*>(x + t + 4 * q);
      buf[4 * q + 0] = v.x;  buf[4 * q + 1] = v.y;
      buf[4 * q + 2] = v.z;  buf[4 * q + 3] = v.w;
    }
#pragma unroll
    for (int s = 0; s < 52; ++s) {
      LPC_STEP(s)
    }
#pragma unroll
    for (int q = 0; q < 13; ++q) {
      float4 v = make_float4(buf[4 * q + 0], buf[4 * q + 1],
                             buf[4 * q + 2], buf[4 * q + 3]);
      *reinterpret_cast<float4*>(op + t + 4 * q) = v;
    }
    t += 52;
  }
  // epilogue: t = 468 (468 % 26 == 0), 44 remaining steps = 11 x float4
#pragma unroll
  for (int q = 0; q < 11; ++q) {
    float4 v = *reinterpret_cast<const float4*>(x + t + 4 * q);
    buf[4 * q + 0] = v.x;  buf[4 * q + 1] = v.y;
    buf[4 * q + 2] = v.z;  buf[4 * q + 3] = v.w;
  }
#pragma unroll
  for (int s = 0; s < 44; ++s) {
    LPC_STEP(s)
  }
#pragma unroll
  for (int q = 0; q < 11; ++q) {
    float4 v = make_float4(buf[4 * q + 0], buf[4 * q + 1],
                           buf[4 * q + 2], buf[4 * q + 3]);
    *reinterpret_cast<float4*>(op + t + 4 * q) = v;
  }
#undef LPC_STEP
}

// ---------------------------------------------------------------------------
// Kernel 3: windowed overlap-add + normalization.
// out[b][j] = ( sum_n fw[b][n][p-128n] * win[p-128n] ) / ( sum_n win[p-128n] ),
// p = j + PAD. 4 outputs per thread; w0 is always a multiple of 4 so every
// frame covers all-4-or-none samples and all float4 accesses are 16B-aligned.
// ---------------------------------------------------------------------------
__global__ __launch_bounds__(256) void k_ola(const float* __restrict__ fw,
                                             const float* __restrict__ win,
                                             float* __restrict__ out) {
  int gid = blockIdx.x * 256 + threadIdx.x;   // one thread per 4 outputs
  const int total4 = BATCH * TLEN / 4;
  if (gid >= total4) return;
  int idx = gid * 4;
  int b  = idx / TLEN;
  int j0 = idx - b * TLEN;
  int p0 = j0 + PAD;

  // frames n with 0 <= p0-128n <= 508:  ceil((p0-508)/128) == (p0-381)/128
  int lo = (p0 - 381) / HOP;
  if (lo < 0) lo = 0;
  int hi = p0 / HOP;
  if (hi > NFRAME - 1) hi = NFRAME - 1;

  float ax = 0.f, ay = 0.f, az = 0.f, aw = 0.f;
  float nx = 0.f, ny = 0.f, nz = 0.f, nw = 0.f;
  for (int n = lo; n <= hi; ++n) {
    int w0 = p0 - n * HOP;       // 0..508, multiple of 4
    const float4 fv = *reinterpret_cast<const float4*>(fw + ((size_t)b * NFRAME + n) * WLEN + w0);
    const float4 wv = *reinterpret_cast<const float4*>(win + w0);
    ax += fv.x * wv.x;  ay += fv.y * wv.y;  az += fv.z * wv.z;  aw += fv.w * wv.w;
    nx += wv.x;         ny += wv.y;         nz += wv.z;         nw += wv.w;
  }
  float4 o = make_float4(ax / nx, ay / ny, az / nz, aw / nw);
  *reinterpret_cast<float4*>(out + idx) = o;
}

// ---------------------------------------------------------------------------
extern "C" void kernel_launch(void* const* d_in, const int* in_sizes, int n_in,
                              void* d_out, int out_size, void* d_ws, size_t ws_size,
                              hipStream_t stream) {
  const float* ex   = (const float*)d_in[0];   // [32][128000]
  const float* gain = (const float*)d_in[1];   // [32][1000]
  const float* a    = (const float*)d_in[2];   // [32][1000][26]
  const float* win  = (const float*)d_in[3];   // [512]
  // d_in[4] = hop_length (=128, compile-time constant here)
  float* outp = (float*)d_out;                 // [32][128000]

  // workspace layout: exg_padded [32][128384] f32, then fw [32][1000][512] f32
  float* exg = (float*)d_ws;
  float* fw  = exg + (size_t)BATCH * TPAD;     // byte offset 16,433,152 (16B aligned)
  // total ws usage: (4,108,288 + 16,384,000) * 4 B ~= 82 MB

  {
    int total4 = BATCH * TPAD / 4;
    int blocks = (total4 + 255) / 256;
    hipLaunchKernelGGL(k_exg, dim3(blocks), dim3(256), 0, stream, ex, gain, exg);
  }
  {
    int blocks = NTOT / 64;                    // 500 blocks x 64, exact
    hipLaunchKernelGGL(k_lpc, dim3(blocks), dim3(64), 0, stream, exg, a, fw);
  }
  {
    int total4 = BATCH * TLEN / 4;
    int blocks = (total4 + 255) / 256;
    hipLaunchKernelGGL(k_ola, dim3(blocks), dim3(256), 0, stream, fw, win, outp);
  }
}